// Round 1
// 2027.305 us; speedup vs baseline: 4.1736x; 4.1736x over previous
//
#include <hip/hip_runtime.h>
#include <hip/hip_bf16.h>

// ClippedGRU: B=256, T=500, I=128, H=512, clip ±5. fp32 in/out, bf16 MFMA core.
//
// Persistent cooperative kernel. Grid = 256 blocks = 16 batch-groups (16 rows
// = MFMA M) x 16 unit-strips (32 h-units -> 96 rows of W_hh/W_ih). W strips
// live in registers as MFMA B-fragments (6 GEMM waves).
//
// This revision removes ALL per-step cache-maintenance (buffer_wbl2/buffer_inv
// from release fences / threadfence): every racing access (h exchange buffer,
// flags) is a RELAXED agent-scope atomic (sc0/sc1 -> serviced coherently at
// the IF point, never stale in L1/L2), so no fences are needed. Ordering of
// h-stores before the flag store is provided by __syncthreads' per-wave
// vmcnt(0) drain (write-through sc1 stores are globally visible once acked).
// Per step: ih GEMM (plain cached loads) -> all waves poll peer flags ->
// cooperative staging of the 16KB h tile into LDS (XOR-swizzled, one far read
// instead of 6 duplicated per-wave reads; ih MFMAs overlap the staging-load
// latency) -> hh GEMM from LDS fragments -> gate math on 128 threads with
// packed 8B h publishes -> barrier (drains publishes) -> relaxed flag store.

#define T_STEPS 500
#define B_TOT   256
#define I_DIM   128
#define H_DIM   512
#define BB      16      // batch rows per group (= MFMA M)
#define UU      32      // h-units per block strip
#define TPAD    512     // padded T for flag indexing
#define FLAGS_BYTES (16 * TPAD * 16)   // [group][t][block] bytes = 128 KB

typedef __bf16 bf16x8 __attribute__((ext_vector_type(8)));
typedef float  f32x4  __attribute__((ext_vector_type(4)));
typedef float  f32x8  __attribute__((ext_vector_type(8)));

__device__ __forceinline__ bf16x8 cvt8(const float* p) {
    f32x8 v = *(const f32x8*)p;   // 32B load (2x dwordx4)
    bf16x8 r;
#pragma unroll
    for (int i = 0; i < 8; ++i) r[i] = (__bf16)v[i];   // RNE cvt
    return r;
}

__device__ __forceinline__ float fast_sigmoid(float x) {
    float e = __builtin_amdgcn_exp2f(-1.4426950408889634f * x);
    return __builtin_amdgcn_rcpf(1.0f + e);
}
__device__ __forceinline__ float fast_tanh(float x) {
    float e = __builtin_amdgcn_exp2f(2.8853900817779268f * x);
    return 1.0f - 2.0f * __builtin_amdgcn_rcpf(1.0f + e);
}

__global__ __launch_bounds__(512, 2)
void gru_persist(const float* __restrict__ x,
                 const float* __restrict__ h0,
                 const float* __restrict__ wih,
                 const float* __restrict__ whh,
                 const float* __restrict__ bih,
                 const float* __restrict__ bhh,
                 float* __restrict__ out,
                 unsigned char* __restrict__ flags,   // [16][TPAD][16], zeroed
                 __hip_bfloat16* __restrict__ hbuf)   // [2][256][512] bf16
{
    const int tid  = threadIdx.x;
    const int bx   = blockIdx.x;
    const int g    = bx >> 4;          // batch group 0..15
    const int j    = bx & 15;          // unit strip 0..15
    const int bg   = g * BB;           // batch base
    const int u0   = j * UU;           // unit base
    const int w    = tid >> 6;         // wave 0..7 (0-5 GEMM)
    const int lane = tid & 63;
    const int lrow = lane & 15;        // MFMA m / n index within fragment
    const int lq   = lane >> 4;        // quad 0..3

    __shared__ float s_g[4][16 * 36];  // r, z, hh_n, xi_n (stride 36, 16B-align)
    __shared__ float s_hold[16 * 32];  // fp32 carried h strip (never rounded)
    __shared__ float s_bih[96];
    __shared__ float s_bhh[96];
    __shared__ __hip_bfloat16 s_h[16 * 512];  // staged h tile, XOR-swizzled

    // ---- one-time init ----
    {
        int b = tid >> 5, u = tid & 31;
        s_hold[b * 32 + u] = h0[(size_t)(bg + b) * H_DIM + u0 + u];
        if (tid < 96) {
            int gg = tid >> 5, uu = tid & 31;
            s_bih[tid] = bih[gg * H_DIM + u0 + uu];
            s_bhh[tid] = bhh[gg * H_DIM + u0 + uu];
        }
    }

    // ---- one-time: W_hh / W_ih strips -> bf16 register B-fragments ----
    const int gate = w >> 1;
    const int hf   = w & 1;
    bf16x8 wf[16], wfi[4];
    if (w < 6) {
        const long row0 = (long)gate * H_DIM + u0 + 16 * hf;  // row in [0,1536)
        const float* wr  = whh + (row0 + lrow) * H_DIM + lq * 8;
        const float* wr2 = wih + (row0 + lrow) * I_DIM + lq * 8;
#pragma unroll
        for (int kt = 0; kt < 16; ++kt) wf[kt] = cvt8(wr + kt * 32);
#pragma unroll
        for (int kt = 0; kt < 4; ++kt)  wfi[kt] = cvt8(wr2 + kt * 32);
    }
    __syncthreads();

    // staging addresses: row sr (0..15), 32B chunk sc (0..31); data granule
    // byte offset within the row is XORed with (row&7)<<4 (T2 swizzle) so the
    // stride-1024B ds_read_b128 fragment reads are bank-conflict-free.
    const int sr = tid >> 5, sc = tid & 31;
    char* sd0 = (char*)s_h + sr * 1024 + ((sc * 32     ) ^ ((sr & 7) << 4));
    char* sd1 = (char*)s_h + sr * 1024 + ((sc * 32 + 16) ^ ((sr & 7) << 4));

    int sync_ok = 1;  // timeout latch (fail-fast, no hang)

#pragma unroll 1
    for (int t = 0; t < T_STEPS; ++t) {
        f32x4 accA = {0, 0, 0, 0}, accB = {0, 0, 0, 0}, accX = {0, 0, 0, 0};

        // ---- A: x fragments for step t (plain cached loads, pre-poll) ----
        bf16x8 xf0, xf1, xf2, xf3;
        if (w < 6) {
            const float* xr =
                x + ((size_t)(bg + lrow) * T_STEPS + t) * I_DIM + lq * 8;
            xf0 = cvt8(xr);
            xf1 = cvt8(xr + 32);
            xf2 = cvt8(xr + 64);
            xf3 = cvt8(xr + 96);
        }

        // ---- B: all waves poll peer flags for step t-1 (relaxed agent) ----
        if (t > 0 && sync_ok) {
            const unsigned long long* fl = (const unsigned long long*)
                (flags + ((size_t)g * TPAD + (t - 1)) * 16);
            long tries = 0;
            for (;;) {
                unsigned long long a = __hip_atomic_load(
                    fl, __ATOMIC_RELAXED, __HIP_MEMORY_SCOPE_AGENT);
                unsigned long long b = __hip_atomic_load(
                    fl + 1, __ATOMIC_RELAXED, __HIP_MEMORY_SCOPE_AGENT);
                if (a == 0x0101010101010101ull &&
                    b == 0x0101010101010101ull) break;
                __builtin_amdgcn_s_sleep(1);
                if (++tries > (1L << 20)) { sync_ok = 0; break; }
            }
        }
        asm volatile("" ::: "memory");   // keep staging loads below the poll

        // ---- C1: issue staging loads (coherent relaxed-agent atomics) ----
        bf16x8 sv0, sv1;
        if (t == 0) {
            const float* hp = h0 + (size_t)(bg + sr) * H_DIM + sc * 16;
            sv0 = cvt8(hp);
            sv1 = cvt8(hp + 8);
        } else {
            const unsigned long long* hp = (const unsigned long long*)
                (hbuf + (size_t)(t & 1) * B_TOT * H_DIM +
                 (size_t)(bg + sr) * H_DIM + sc * 16);
            unsigned long long q0 = __hip_atomic_load(
                hp + 0, __ATOMIC_RELAXED, __HIP_MEMORY_SCOPE_AGENT);
            unsigned long long q1 = __hip_atomic_load(
                hp + 1, __ATOMIC_RELAXED, __HIP_MEMORY_SCOPE_AGENT);
            unsigned long long q2 = __hip_atomic_load(
                hp + 2, __ATOMIC_RELAXED, __HIP_MEMORY_SCOPE_AGENT);
            unsigned long long q3 = __hip_atomic_load(
                hp + 3, __ATOMIC_RELAXED, __HIP_MEMORY_SCOPE_AGENT);
            union { unsigned long long q[2]; bf16x8 v; } ua, ub;
            ua.q[0] = q0; ua.q[1] = q1;
            ub.q[0] = q2; ub.q[1] = q3;
            sv0 = ua.v;
            sv1 = ub.v;
        }

        // ---- C2: ih GEMM MFMAs (overlap staging-load latency) ----
        if (w < 6) {
            f32x4 ai = {0, 0, 0, 0};
            ai = __builtin_amdgcn_mfma_f32_16x16x32_bf16(xf0, wfi[0], ai, 0, 0, 0);
            ai = __builtin_amdgcn_mfma_f32_16x16x32_bf16(xf1, wfi[1], ai, 0, 0, 0);
            ai = __builtin_amdgcn_mfma_f32_16x16x32_bf16(xf2, wfi[2], ai, 0, 0, 0);
            ai = __builtin_amdgcn_mfma_f32_16x16x32_bf16(xf3, wfi[3], ai, 0, 0, 0);
            if (gate < 2) accA = ai; else accX = ai;
        }

        // ---- C3: write staged tile to LDS ----
        *(bf16x8*)sd0 = sv0;
        *(bf16x8*)sd1 = sv1;
        __syncthreads();                               // D

        // ---- E: hh GEMM: A = LDS h fragments, B = register W ----
        if (w < 6) {
            const char* ab  = (const char*)s_h + lrow * 1024;
            const int   swz = (lrow & 7) << 4;
#pragma unroll
            for (int kt = 0; kt < 8; ++kt) {
                bf16x8 hfr = *(const bf16x8*)(ab + ((lq * 16 + kt * 64) ^ swz));
                accA = __builtin_amdgcn_mfma_f32_16x16x32_bf16(hfr, wf[kt],
                                                               accA, 0, 0, 0);
            }
#pragma unroll
            for (int kt = 8; kt < 16; ++kt) {
                bf16x8 hfr = *(const bf16x8*)(ab + ((lq * 16 + kt * 64) ^ swz));
                accB = __builtin_amdgcn_mfma_f32_16x16x32_bf16(hfr, wf[kt],
                                                               accB, 0, 0, 0);
            }
            // C layout: col = lane&15 (unit), row = (lane>>4)*4+i (batch)
            const int col = hf * 16 + lrow;
#pragma unroll
            for (int i = 0; i < 4; ++i) {
                int b = lq * 4 + i;
                s_g[gate][b * 36 + col] = accA[i] + accB[i];
                if (gate == 2) s_g[3][b * 36 + col] = accX[i];
            }
        }
        __syncthreads();                               // F

        // ---- G: gate math, 128 threads x 4 units, packed 8B publish ----
        if (tid < 128) {
            const int b  = tid >> 3;
            const int ub = (tid & 7) * 4;
            f32x4 vr  = *(const f32x4*)&s_g[0][b * 36 + ub];
            f32x4 vz  = *(const f32x4*)&s_g[1][b * 36 + ub];
            f32x4 vhn = *(const f32x4*)&s_g[2][b * 36 + ub];
            f32x4 vxn = *(const f32x4*)&s_g[3][b * 36 + ub];
            f32x4 hold = *(const f32x4*)&s_hold[b * 32 + ub];
            f32x4 hnew;
            unsigned long long pk = 0;
#pragma unroll
            for (int i = 0; i < 4; ++i) {
                float rr = fast_sigmoid(vr[i] + s_bih[ub + i] + s_bhh[ub + i]);
                float zz = fast_sigmoid(vz[i] + s_bih[32 + ub + i] +
                                        s_bhh[32 + ub + i]);
                float nn = fast_tanh(vxn[i] + s_bih[64 + ub + i] +
                                     rr * (vhn[i] + s_bhh[64 + ub + i]));
                float hv = (1.0f - zz) * nn + zz * hold[i];
                hv = fminf(fmaxf(hv, -5.0f), 5.0f);
                hnew[i] = hv;
                __bf16 hb = (__bf16)hv;
                pk |= (unsigned long long)__builtin_bit_cast(unsigned short, hb)
                      << (16 * i);
            }
            *(f32x4*)&s_hold[b * 32 + ub] = hnew;
            *(f32x4*)(out + ((size_t)(bg + b) * T_STEPS + t) * H_DIM + u0 + ub)
                = hnew;
            __hip_atomic_store(
                (unsigned long long*)(hbuf +
                    (size_t)((t + 1) & 1) * B_TOT * H_DIM +
                    (size_t)(bg + b) * H_DIM + u0 + ub),
                pk, __ATOMIC_RELAXED, __HIP_MEMORY_SCOPE_AGENT);
            if (t == T_STEPS - 1)
                *(f32x4*)(out + (size_t)B_TOT * T_STEPS * H_DIM +
                          (size_t)(bg + b) * H_DIM + u0 + ub) = hnew;
        }
        __syncthreads();   // H: per-wave vmcnt(0) drain -> publishes visible

        // ---- I: relaxed flag store (no wbl2 -- sc1 data already coherent) --
        if (tid == 0 && t < T_STEPS - 1) {
            __hip_atomic_store(flags + ((size_t)g * TPAD + t) * 16 + j,
                               (unsigned char)1, __ATOMIC_RELAXED,
                               __HIP_MEMORY_SCOPE_AGENT);
        }
    }
}

extern "C" void kernel_launch(void* const* d_in, const int* in_sizes, int n_in,
                              void* d_out, int out_size, void* d_ws, size_t ws_size,
                              hipStream_t stream) {
    const float* x   = (const float*)d_in[0];
    const float* h0  = (const float*)d_in[1];
    const float* wih = (const float*)d_in[2];
    const float* whh = (const float*)d_in[3];
    const float* bih = (const float*)d_in[4];
    const float* bhh = (const float*)d_in[5];
    float* out = (float*)d_out;
    unsigned char*  flags = (unsigned char*)d_ws;
    __hip_bfloat16* hbuf  = (__hip_bfloat16*)((char*)d_ws + FLAGS_BYTES);

    // flags must start at 0 every launch (ws is re-poisoned to 0xAA).
    hipMemsetAsync(d_ws, 0, FLAGS_BYTES, stream);

    void* args[] = { (void*)&x, (void*)&h0, (void*)&wih, (void*)&whh,
                     (void*)&bih, (void*)&bhh, (void*)&out,
                     (void*)&flags, (void*)&hbuf };
    // Cooperative launch guarantees all 256 blocks (1/CU) are co-resident,
    // which the group-local flag barriers require.
    hipLaunchCooperativeKernel((void*)gru_persist, dim3(256), dim3(512),
                               args, 0, stream);
}